// Round 1
// baseline (1883.208 us; speedup 1.0000x reference)
//
#include <hip/hip_runtime.h>
#include <math.h>

// Problem constants (B,T,D,H from reference)
#define NB   16
#define TSEQ 16384
#define DD   128
#define HH   256
constexpr float EPS = 1e-5f;

// GEMM tiling: 256 threads, 64-row x 128-col tile, K-chunk 32, 8x4 micro-tile.
constexpr int BM = 64;
constexpr int BK = 32;
constexpr int NT = 256;

// Float atomic max via int/uint monotonicity trick (init to -inf).
__device__ __forceinline__ void atomicMaxFloat(float* addr, float val) {
    if (val >= 0.0f) atomicMax((int*)addr, __float_as_int(val));
    else             atomicMin((unsigned int*)addr, __float_as_uint(val));
}

// ---------------------------------------------------------------------------
// C = A @ W^T   (A: [M,128] row-major, W: [128,128] row-major)
// ---------------------------------------------------------------------------
__global__ __launch_bounds__(NT) void gemm_proj(const float* __restrict__ A,
                                                const float* __restrict__ W,
                                                float* __restrict__ C)
{
    // padding +4 keeps rows 16B-aligned for ds b128 access
    __shared__ float sA[BK][BM + 4];
    __shared__ float sW[BK][DD + 4];
    const int tid  = threadIdx.x;
    const long m0  = (long)blockIdx.x * BM;
    const int trow = tid >> 5;         // 0..7
    const int tcol = tid & 31;         // 0..31
    const int lr   = tid >> 3;         // 0..31
    const int lc   = (tid & 7) << 2;   // 0,4,...,28
    float acc[8][4] = {};

    for (int k0 = 0; k0 < DD; k0 += BK) {
#pragma unroll
        for (int i = 0; i < 2; ++i) {  // A chunk [64][32], transposed into LDS
            const int r = lr + i * 32;
            const float4 a4 = *(const float4*)(A + (m0 + r) * DD + k0 + lc);
            sA[lc + 0][r] = a4.x; sA[lc + 1][r] = a4.y;
            sA[lc + 2][r] = a4.z; sA[lc + 3][r] = a4.w;
        }
#pragma unroll
        for (int i = 0; i < 4; ++i) {  // W chunk [128][32], transposed into LDS
            const int r = lr + i * 32;
            const float4 w4 = *(const float4*)(W + (long)r * DD + k0 + lc);
            sW[lc + 0][r] = w4.x; sW[lc + 1][r] = w4.y;
            sW[lc + 2][r] = w4.z; sW[lc + 3][r] = w4.w;
        }
        __syncthreads();
#pragma unroll
        for (int kk = 0; kk < BK; ++kk) {
            const float4 a0 = *(const float4*)&sA[kk][trow * 8];
            const float4 a1 = *(const float4*)&sA[kk][trow * 8 + 4];
            const float4 w0 = *(const float4*)&sW[kk][tcol * 4];
            const float a[8] = {a0.x, a0.y, a0.z, a0.w, a1.x, a1.y, a1.z, a1.w};
            const float w[4] = {w0.x, w0.y, w0.z, w0.w};
#pragma unroll
            for (int i = 0; i < 8; ++i)
#pragma unroll
                for (int j = 0; j < 4; ++j)
                    acc[i][j] = fmaf(a[i], w[j], acc[i][j]);
        }
        __syncthreads();
    }
#pragma unroll
    for (int i = 0; i < 8; ++i) {
        const float4 o4 = make_float4(acc[i][0], acc[i][1], acc[i][2], acc[i][3]);
        *(float4*)(C + (m0 + trow * 8 + i) * DD + tcol * 4) = o4;
    }
}

// ---------------------------------------------------------------------------
// Hadamard feature map, IN PLACE:  A <- (A@W1^T + b1) * (A@W2^T + b2)
// Safe in-place: block only writes rows it alone reads, and the final
// __syncthreads() of the k-loop orders all loads before any store.
// ---------------------------------------------------------------------------
__global__ __launch_bounds__(NT) void gemm_fm(float* __restrict__ A,
                                              const float* __restrict__ W1,
                                              const float* __restrict__ B1,
                                              const float* __restrict__ W2,
                                              const float* __restrict__ B2)
{
    __shared__ float sA[BK][BM + 4];
    __shared__ float sW1[BK][DD + 4];
    __shared__ float sW2[BK][DD + 4];
    const int tid  = threadIdx.x;
    const long m0  = (long)blockIdx.x * BM;
    const int trow = tid >> 5;
    const int tcol = tid & 31;
    const int lr   = tid >> 3;
    const int lc   = (tid & 7) << 2;
    float acc1[8][4] = {};
    float acc2[8][4] = {};

    for (int k0 = 0; k0 < DD; k0 += BK) {
#pragma unroll
        for (int i = 0; i < 2; ++i) {
            const int r = lr + i * 32;
            const float4 a4 = *(const float4*)(A + (m0 + r) * DD + k0 + lc);
            sA[lc + 0][r] = a4.x; sA[lc + 1][r] = a4.y;
            sA[lc + 2][r] = a4.z; sA[lc + 3][r] = a4.w;
        }
#pragma unroll
        for (int i = 0; i < 4; ++i) {
            const int r = lr + i * 32;
            const float4 w4 = *(const float4*)(W1 + (long)r * DD + k0 + lc);
            sW1[lc + 0][r] = w4.x; sW1[lc + 1][r] = w4.y;
            sW1[lc + 2][r] = w4.z; sW1[lc + 3][r] = w4.w;
            const float4 v4 = *(const float4*)(W2 + (long)r * DD + k0 + lc);
            sW2[lc + 0][r] = v4.x; sW2[lc + 1][r] = v4.y;
            sW2[lc + 2][r] = v4.z; sW2[lc + 3][r] = v4.w;
        }
        __syncthreads();
#pragma unroll
        for (int kk = 0; kk < BK; ++kk) {
            const float4 a0 = *(const float4*)&sA[kk][trow * 8];
            const float4 a1 = *(const float4*)&sA[kk][trow * 8 + 4];
            const float4 u0 = *(const float4*)&sW1[kk][tcol * 4];
            const float4 v0 = *(const float4*)&sW2[kk][tcol * 4];
            const float a[8] = {a0.x, a0.y, a0.z, a0.w, a1.x, a1.y, a1.z, a1.w};
            const float u[4] = {u0.x, u0.y, u0.z, u0.w};
            const float v[4] = {v0.x, v0.y, v0.z, v0.w};
#pragma unroll
            for (int i = 0; i < 8; ++i) {
#pragma unroll
                for (int j = 0; j < 4; ++j) {
                    acc1[i][j] = fmaf(a[i], u[j], acc1[i][j]);
                    acc2[i][j] = fmaf(a[i], v[j], acc2[i][j]);
                }
            }
        }
        __syncthreads();
    }
    const float4 b1v = *(const float4*)&B1[tcol * 4];
    const float4 b2v = *(const float4*)&B2[tcol * 4];
    const float b1a[4] = {b1v.x, b1v.y, b1v.z, b1v.w};
    const float b2a[4] = {b2v.x, b2v.y, b2v.z, b2v.w};
#pragma unroll
    for (int i = 0; i < 8; ++i) {
        float4 o4;
        o4.x = (acc1[i][0] + b1a[0]) * (acc2[i][0] + b2a[0]);
        o4.y = (acc1[i][1] + b1a[1]) * (acc2[i][1] + b2a[1]);
        o4.z = (acc1[i][2] + b1a[2]) * (acc2[i][2] + b2a[2]);
        o4.w = (acc1[i][3] + b1a[3]) * (acc2[i][3] + b2a[3]);
        *(float4*)(A + (m0 + trow * 8 + i) * DD + tcol * 4) = o4;
    }
}

// ---------------------------------------------------------------------------
// Zero S and set pooled to -inf (ws is re-poisoned to 0xAA before each call).
// ---------------------------------------------------------------------------
__global__ void init_ws(float* __restrict__ S, float* __restrict__ pooled)
{
    const int i = blockIdx.x * blockDim.x + threadIdx.x;
    if (i < NB * DD * DD) S[i] = 0.0f;
    if (i < NB * DD)      pooled[i] = -INFINITY;
}

// ---------------------------------------------------------------------------
// S[b] += kf[b,chunk]^T @ v[b,chunk]  -- [128,128] per batch, atomicAdd merge.
// grid: (chunks, NB). 256 threads, each owns an 8x8 (d,e) micro-tile.
// ---------------------------------------------------------------------------
constexpr int S_CHUNKS = 64;                 // blocks per batch
constexpr int S_ROWS   = TSEQ / S_CHUNKS;    // 256 rows per block
constexpr int S_STAGE  = 8;

__global__ __launch_bounds__(NT) void kv_state(const float* __restrict__ kf,
                                               const float* __restrict__ v,
                                               float* __restrict__ S)
{
    const int b    = blockIdx.y;
    const int row0 = blockIdx.x * S_ROWS;
    const float* kb = kf + (long)b * TSEQ * DD;
    const float* vb = v  + (long)b * TSEQ * DD;
    __shared__ float sk[S_STAGE][DD];
    __shared__ float sv[S_STAGE][DD];
    const int tid = threadIdx.x;
    const int td  = tid >> 4;          // 0..15 -> d block
    const int te  = tid & 15;          // 0..15 -> e block
    const int lr  = tid >> 5;          // 0..7
    const int lc  = (tid & 31) << 2;   // 0..124
    float acc[8][8] = {};

    for (int r0 = row0; r0 < row0 + S_ROWS; r0 += S_STAGE) {
        *(float4*)&sk[lr][lc] = *(const float4*)(kb + (long)(r0 + lr) * DD + lc);
        *(float4*)&sv[lr][lc] = *(const float4*)(vb + (long)(r0 + lr) * DD + lc);
        __syncthreads();
#pragma unroll
        for (int rr = 0; rr < S_STAGE; ++rr) {
            const float4 k0 = *(const float4*)&sk[rr][td * 8];
            const float4 k1 = *(const float4*)&sk[rr][td * 8 + 4];
            const float4 e0 = *(const float4*)&sv[rr][te * 8];
            const float4 e1 = *(const float4*)&sv[rr][te * 8 + 4];
            const float kd[8] = {k0.x, k0.y, k0.z, k0.w, k1.x, k1.y, k1.z, k1.w};
            const float ve[8] = {e0.x, e0.y, e0.z, e0.w, e1.x, e1.y, e1.z, e1.w};
#pragma unroll
            for (int i = 0; i < 8; ++i)
#pragma unroll
                for (int j = 0; j < 8; ++j)
                    acc[i][j] = fmaf(kd[i], ve[j], acc[i][j]);
        }
        __syncthreads();
    }
    float* Sb = S + (long)b * DD * DD;
#pragma unroll
    for (int i = 0; i < 8; ++i)
#pragma unroll
        for (int j = 0; j < 8; ++j)
            atomicAdd(&Sb[(td * 8 + i) * DD + te * 8 + j], acc[i][j]);
}

// ---------------------------------------------------------------------------
// Fused o-stage per 64-row tile:
//   o = qf @ S[b]  ->  RMSNorm(o)*rms_w  ->  y = o @ Wo^T  ->  colmax -> pooled
// o never touches HBM.
// ---------------------------------------------------------------------------
__global__ __launch_bounds__(NT) void ostage(const float* __restrict__ qf,
                                             const float* __restrict__ S,
                                             const float* __restrict__ rmsw,
                                             const float* __restrict__ Wo,
                                             float* __restrict__ pooled)
{
    const long m0 = (long)blockIdx.x * BM;
    const int b   = (int)(m0 / TSEQ);           // 64 | 16384, no straddle
    __shared__ float sq[BM][DD + 4];            // qf tile, then o_norm tile
    __shared__ float sw[BK][DD + 4];            // S chunk, then Wo chunk
    __shared__ float sred[8][DD];               // maxpool reduction
    const int tid  = threadIdx.x;
    const int trow = tid >> 5;
    const int tcol = tid & 31;

    // load qf tile [64][128]
#pragma unroll
    for (int i = 0; i < 8; ++i) {
        const int r = (tid >> 5) + i * 8;
        const int c = (tid & 31) << 2;
        *(float4*)&sq[r][c] = *(const float4*)(qf + (m0 + r) * DD + c);
    }
    __syncthreads();

    // ---- o = qf @ S[b]  (S is [d][e]: already W^T-layout for this product)
    float acc[8][4] = {};
    const float* Sb = S + (long)b * DD * DD;
    for (int k0 = 0; k0 < DD; k0 += BK) {
#pragma unroll
        for (int i = 0; i < 4; ++i) {  // stage S rows k0..k0+31 directly
            const int rr = (tid >> 5) + i * 8;
            const int c  = (tid & 31) << 2;
            *(float4*)&sw[rr][c] = *(const float4*)(Sb + (long)(k0 + rr) * DD + c);
        }
        __syncthreads();
#pragma unroll
        for (int kk = 0; kk < BK; ++kk) {
            const float4 w0 = *(const float4*)&sw[kk][tcol * 4];
            const float w[4] = {w0.x, w0.y, w0.z, w0.w};
#pragma unroll
            for (int i = 0; i < 8; ++i) {
                const float a = sq[trow * 8 + i][k0 + kk];
#pragma unroll
                for (int j = 0; j < 4; ++j)
                    acc[i][j] = fmaf(a, w[j], acc[i][j]);
            }
        }
        __syncthreads();
    }

    // ---- RMSNorm over the 128-wide row (held by 32 consecutive lanes)
    const float4 rw4 = *(const float4*)&rmsw[tcol * 4];
    const float rw[4] = {rw4.x, rw4.y, rw4.z, rw4.w};
    float scale[8];
#pragma unroll
    for (int i = 0; i < 8; ++i) {
        float ss = acc[i][0] * acc[i][0] + acc[i][1] * acc[i][1]
                 + acc[i][2] * acc[i][2] + acc[i][3] * acc[i][3];
#pragma unroll
        for (int m = 16; m >= 1; m >>= 1) ss += __shfl_xor(ss, m, 32);
        scale[i] = rsqrtf(ss * (1.0f / DD) + EPS);
    }
    // write o_norm back into sq (all reads of qf done: k-loop ended w/ barrier)
#pragma unroll
    for (int i = 0; i < 8; ++i) {
        float4 o4;
        o4.x = acc[i][0] * scale[i] * rw[0];
        o4.y = acc[i][1] * scale[i] * rw[1];
        o4.z = acc[i][2] * scale[i] * rw[2];
        o4.w = acc[i][3] * scale[i] * rw[3];
        *(float4*)&sq[trow * 8 + i][tcol * 4] = o4;
    }
    __syncthreads();

    // ---- y = o_norm @ Wo^T
    float accy[8][4] = {};
    const int lr = tid >> 3;
    const int lc = (tid & 7) << 2;
    for (int k0 = 0; k0 < DD; k0 += BK) {
#pragma unroll
        for (int i = 0; i < 4; ++i) {  // stage Wo chunk transposed
            const int r = lr + i * 32;
            const float4 w4 = *(const float4*)(Wo + (long)r * DD + k0 + lc);
            sw[lc + 0][r] = w4.x; sw[lc + 1][r] = w4.y;
            sw[lc + 2][r] = w4.z; sw[lc + 3][r] = w4.w;
        }
        __syncthreads();
#pragma unroll
        for (int kk = 0; kk < BK; ++kk) {
            const float4 w0 = *(const float4*)&sw[kk][tcol * 4];
            const float w[4] = {w0.x, w0.y, w0.z, w0.w};
#pragma unroll
            for (int i = 0; i < 8; ++i) {
                const float a = sq[trow * 8 + i][k0 + kk];
#pragma unroll
                for (int j = 0; j < 4; ++j)
                    accy[i][j] = fmaf(a, w[j], accy[i][j]);
            }
        }
        __syncthreads();
    }

    // ---- maxpool over the tile's 64 rows
    float cmax[4];
#pragma unroll
    for (int j = 0; j < 4; ++j) {
        float m = accy[0][j];
#pragma unroll
        for (int i = 1; i < 8; ++i) m = fmaxf(m, accy[i][j]);
        cmax[j] = m;
    }
#pragma unroll
    for (int j = 0; j < 4; ++j) sred[trow][tcol * 4 + j] = cmax[j];
    __syncthreads();
    if (tid < DD) {
        float m = sred[0][tid];
#pragma unroll
        for (int r = 1; r < 8; ++r) m = fmaxf(m, sred[r][tid]);
        atomicMaxFloat(&pooled[b * DD + tid], m);
    }
}

// ---------------------------------------------------------------------------
// out[b,h] = pooled[b] . Wp[h] + bp[h]   (16 x 256, tiny)
// ---------------------------------------------------------------------------
__global__ __launch_bounds__(HH) void final_proj(const float* __restrict__ pooled,
                                                 const float* __restrict__ Wp,
                                                 const float* __restrict__ bp,
                                                 float* __restrict__ out)
{
    const int b = blockIdx.x;
    const int h = threadIdx.x;
    __shared__ float sp[DD];
    if (h < DD) sp[h] = pooled[b * DD + h];
    __syncthreads();
    float acc = bp[h];
#pragma unroll 8
    for (int d = 0; d < DD; ++d) acc = fmaf(sp[d], Wp[(long)h * DD + d], acc);
    out[b * HH + h] = acc;
}

// ---------------------------------------------------------------------------
extern "C" void kernel_launch(void* const* d_in, const int* in_sizes, int n_in,
                              void* d_out, int out_size, void* d_ws, size_t ws_size,
                              hipStream_t stream)
{
    const float* x      = (const float*)d_in[0];
    const float* Wq     = (const float*)d_in[1];
    const float* Wk     = (const float*)d_in[2];
    const float* Wv     = (const float*)d_in[3];
    const float* fmq_w1 = (const float*)d_in[4];
    const float* fmq_b1 = (const float*)d_in[5];
    const float* fmq_w2 = (const float*)d_in[6];
    const float* fmq_b2 = (const float*)d_in[7];
    const float* fmk_w1 = (const float*)d_in[8];
    const float* fmk_b1 = (const float*)d_in[9];
    const float* fmk_w2 = (const float*)d_in[10];
    const float* fmk_b2 = (const float*)d_in[11];
    const float* rms_w  = (const float*)d_in[12];
    const float* Wo     = (const float*)d_in[13];
    const float* Wp     = (const float*)d_in[14];
    const float* bp     = (const float*)d_in[15];
    float* out = (float*)d_out;

    // workspace layout (floats): 3 big [B*T,D] buffers + S + pooled (~386 MB)
    float* ws   = (float*)d_ws;
    const long nElem = (long)NB * TSEQ * DD;  // 33,554,432
    float* bufA   = ws;                 // q  -> qf (in place)
    float* bufB   = ws + nElem;         // k  -> kf (in place)
    float* bufC   = ws + 2 * nElem;     // v
    float* S      = ws + 3 * nElem;     // [NB,128,128]
    float* pooled = S + NB * DD * DD;   // [NB,128]

    const int M = NB * TSEQ;            // 262144 rows
    const int gTiles = M / BM;          // 4096 blocks

    gemm_proj<<<gTiles, NT, 0, stream>>>(x, Wq, bufA);
    gemm_proj<<<gTiles, NT, 0, stream>>>(x, Wk, bufB);
    gemm_proj<<<gTiles, NT, 0, stream>>>(x, Wv, bufC);
    gemm_fm  <<<gTiles, NT, 0, stream>>>(bufA, fmq_w1, fmq_b1, fmq_w2, fmq_b2);
    gemm_fm  <<<gTiles, NT, 0, stream>>>(bufB, fmk_w1, fmk_b1, fmk_w2, fmk_b2);
    init_ws  <<<(NB * DD * DD + NT - 1) / NT, NT, 0, stream>>>(S, pooled);
    kv_state <<<dim3(S_CHUNKS, NB), NT, 0, stream>>>(bufB, bufC, S);
    ostage   <<<gTiles, NT, 0, stream>>>(bufA, S, rms_w, Wo, pooled);
    final_proj<<<NB, HH, 0, stream>>>(pooled, Wp, bp, out);
}

// Round 3
// 615.109 us; speedup vs baseline: 3.0616x; 3.0616x over previous
//
#include <hip/hip_runtime.h>
#include <math.h>

#define NB   16
#define TSEQ 16384
#define DD   128
#define HH   256
constexpr float EPS = 1e-5f;

typedef _Float16 h8v __attribute__((ext_vector_type(8)));
typedef _Float16 h4v __attribute__((ext_vector_type(4)));
typedef float    f4v __attribute__((ext_vector_type(4)));

#define MFMA16(a, b, c) __builtin_amdgcn_mfma_f32_16x16x32_f16(a, b, c, 0, 0, 0)

// LDS strides (halves). 136*2=272B: 16B-aligned rows, 68-word stride -> 2-way
// bank alias only (free). 72*2=144B: aligned, 36-word stride -> <=4-way.
constexpr int SX_S = 136;
constexpr int SW_S = 136;
constexpr int ST_S = 72;
constexpr int K1_BM = 64;

__device__ __forceinline__ void atomicMaxFloat(float* addr, float val) {
    if (val >= 0.0f) atomicMax((int*)addr, __float_as_int(val));
    else             atomicMin((unsigned int*)addr, __float_as_uint(val));
}

// ---------------------------------------------------------------------------
// K0: weights fp32->fp16 (rms_w folded into Wo), zero S^T, init pooled.
// Wh order: 0 Wq, 1 Wk, 2 Wv, 3 fq1, 4 fq2, 5 fk1, 6 fk2, 7 Wo*rms_w
// ---------------------------------------------------------------------------
__global__ __launch_bounds__(256) void k0_prep(
    const float* __restrict__ Wq, const float* __restrict__ Wk,
    const float* __restrict__ Wv, const float* __restrict__ fq1,
    const float* __restrict__ fq2, const float* __restrict__ fk1,
    const float* __restrict__ fk2, const float* __restrict__ Wo,
    const float* __restrict__ rmsw,
    _Float16* __restrict__ Wh, float* __restrict__ STf,
    float* __restrict__ pooled)
{
    const int i = blockIdx.x * 256 + threadIdx.x;
    if (i < 8 * DD * DD) {
        const int mat = i >> 14;
        const int e   = i & (DD * DD - 1);
        const float* srcs[8] = {Wq, Wk, Wv, fq1, fq2, fk1, fk2, Wo};
        float v = srcs[mat][e];
        if (mat == 7) v *= rmsw[e & (DD - 1)];
        Wh[i] = (_Float16)v;
    }
    if (i < NB * DD * DD) STf[i] = 0.0f;
    if (i < NB * DD)      pooled[i] = -INFINITY;
}

// ---------------------------------------------------------------------------
// K1: fused qkv + feature maps. Per 64-row tile:
//   q=x@Wq^T; qf=(q@W1^T+b1)*(q@W2^T+b2)  -> qf   [t][d] fp16
//   k=x@Wk^T; kf=(...)                    -> kfT  [d][t] fp16
//   v=x@Wv^T                              -> vT   [e][t] fp16
// MFMA frags (16x16x32): A[m=l&15][k=q*8+j], B[k=q*8+j][n=l&15],
// C[m=q*4+r][n=l&15]. Activations [t][d] and weights [n][k] are both
// k-contiguous -> transpose-free b128 LDS reads.
// ---------------------------------------------------------------------------
__global__ __launch_bounds__(256) void k1_qkvfm(
    const float* __restrict__ x, const _Float16* __restrict__ Wh,
    const float* __restrict__ bq1, const float* __restrict__ bq2,
    const float* __restrict__ bk1, const float* __restrict__ bk2,
    _Float16* __restrict__ qf, _Float16* __restrict__ kfT,
    _Float16* __restrict__ vT)
{
    __shared__ _Float16 sX[K1_BM * SX_S];   // x tile fp16
    __shared__ _Float16 sW[DD * SW_S];      // current weight
    __shared__ _Float16 sC[K1_BM * SX_S];   // chain buffer [t][d]
    __shared__ _Float16 sT[DD * ST_S];      // transposed out [d][t]

    const int tid = threadIdx.x;
    const int wv = tid >> 6, ln = tid & 63, lm = ln & 15, lq = ln >> 4;
    const long t0 = (long)blockIdx.x * K1_BM;
    const int b = (int)(t0 >> 14), tin = (int)(t0 & (TSEQ - 1));

    // stage x -> sX (fp32 -> fp16)
    {
        const int r = tid >> 2, c0 = (tid & 3) * 32;
        const float* src = x + (t0 + r) * DD + c0;
        _Float16* dst = sX + r * SX_S + c0;
#pragma unroll
        for (int i = 0; i < 8; ++i) {
            const float4 v = *(const float4*)(src + i * 4);
            h4v h; h[0] = (_Float16)v.x; h[1] = (_Float16)v.y;
                   h[2] = (_Float16)v.z; h[3] = (_Float16)v.w;
            *(h4v*)(dst + i * 4) = h;
        }
    }

    auto stageW = [&](int mat) {
        const _Float16* src = Wh + mat * DD * DD + (tid >> 1) * DD + (tid & 1) * 64;
        _Float16* dst = sW + (tid >> 1) * SW_S + (tid & 1) * 64;
#pragma unroll
        for (int i = 0; i < 8; ++i) *(h8v*)(dst + i * 8) = *(const h8v*)(src + i * 8);
    };
    auto gemm = [&](const _Float16* sA, f4v* acc) {
#pragma unroll
        for (int k0 = 0; k0 < 4; ++k0) {
            const h8v a = *(const h8v*)(sA + (wv * 16 + lm) * SX_S + k0 * 32 + lq * 8);
#pragma unroll
            for (int nt = 0; nt < 8; ++nt) {
                const h8v bb = *(const h8v*)(sW + (nt * 16 + lm) * SW_S + k0 * 32 + lq * 8);
                acc[nt] = MFMA16(a, bb, acc[nt]);
            }
        }
    };
    auto zero8 = [&](f4v* a) {
#pragma unroll
        for (int i = 0; i < 8; ++i) { a[i][0] = 0.f; a[i][1] = 0.f; a[i][2] = 0.f; a[i][3] = 0.f; }
    };
    auto cToC = [&](const f4v* acc) {  // C frags -> sC [t][d] (scalar u16, ~free 2-way)
#pragma unroll
        for (int nt = 0; nt < 8; ++nt)
#pragma unroll
            for (int r = 0; r < 4; ++r)
                sC[(wv * 16 + lq * 4 + r) * SX_S + nt * 16 + lm] = (_Float16)acc[nt][r];
    };
    auto cToT = [&](const f4v* acc) {  // C frags -> sT [d][t] (b64: 4 consecutive t)
#pragma unroll
        for (int nt = 0; nt < 8; ++nt) {
            h4v h;
#pragma unroll
            for (int r = 0; r < 4; ++r) h[r] = (_Float16)acc[nt][r];
            *(h4v*)(sT + (nt * 16 + lm) * ST_S + wv * 16 + lq * 4) = h;
        }
    };
    // FIXED (R2 bug): sC is a 64-row tile. Old pattern (tid>>1, (tid&1)*64)
    // covered 128 rows -> OOB LDS reads + racy writes into the next block's
    // qf region. Now 64 rows x 128 cols, 4x h8v per thread.
    auto copyC_global = [&](_Float16* dst0) {
        const int r = tid >> 2, c0 = (tid & 3) * 32;
        _Float16* dst = dst0 + (t0 + r) * DD + c0;
        const _Float16* src = sC + r * SX_S + c0;
#pragma unroll
        for (int i = 0; i < 4; ++i) *(h8v*)(dst + i * 8) = *(const h8v*)(src + i * 8);
    };
    auto copyT_global = [&](_Float16* dst0) {
        const int d = tid >> 1, c0 = (tid & 1) * 32;
        _Float16* dst = dst0 + ((long)b * DD + d) * TSEQ + tin + c0;
        const _Float16* src = sT + d * ST_S + c0;
#pragma unroll
        for (int i = 0; i < 4; ++i) *(h8v*)(dst + i * 8) = *(const h8v*)(src + i * 8);
    };

    f4v a1[8], a2[8];

    // ---------------- Q chain: q -> fmq1/fmq2 -> qf (natural [t][d])
    stageW(0); __syncthreads();
    zero8(a1); gemm(sX, a1); cToC(a1);          // sC = q
    __syncthreads();
    stageW(3); __syncthreads();
    zero8(a1); gemm(sC, a1);                    // fq1
    __syncthreads();
    stageW(4); __syncthreads();
    zero8(a2); gemm(sC, a2);                    // fq2
    __syncthreads();                            // all reads of sC done
#pragma unroll
    for (int nt = 0; nt < 8; ++nt) {
        const float b1 = bq1[nt * 16 + lm], b2 = bq2[nt * 16 + lm];
#pragma unroll
        for (int r = 0; r < 4; ++r) a1[nt][r] = (a1[nt][r] + b1) * (a2[nt][r] + b2);
    }
    cToC(a1); __syncthreads();
    copyC_global(qf); __syncthreads();

    // ---------------- K chain: k -> fmk1/fmk2 -> kfT (transposed [d][t])
    stageW(1); __syncthreads();
    zero8(a1); gemm(sX, a1); cToC(a1);          // sC = k
    __syncthreads();
    stageW(5); __syncthreads();
    zero8(a1); gemm(sC, a1);                    // fk1
    __syncthreads();
    stageW(6); __syncthreads();
    zero8(a2); gemm(sC, a2);                    // fk2
    __syncthreads();
#pragma unroll
    for (int nt = 0; nt < 8; ++nt) {
        const float b1 = bk1[nt * 16 + lm], b2 = bk2[nt * 16 + lm];
#pragma unroll
        for (int r = 0; r < 4; ++r) a1[nt][r] = (a1[nt][r] + b1) * (a2[nt][r] + b2);
    }
    cToT(a1); __syncthreads();
    copyT_global(kfT); __syncthreads();

    // ---------------- V: v -> vT (transposed [e][t])
    stageW(2); __syncthreads();
    zero8(a1); gemm(sX, a1);
    cToT(a1); __syncthreads();
    copyT_global(vT);
}

// ---------------------------------------------------------------------------
// K2: S^T[b][e][d] += sum_t vT[e][t] * kfT[d][t]   (MFMA, k = t)
// grid (T/512, NB); per block 8 staged 64-t chunks; fp32 atomicAdd partials.
// ---------------------------------------------------------------------------
constexpr int K2_KT = 512;
constexpr int K2_TC = 64;

__global__ __launch_bounds__(256) void k2_kv(const _Float16* __restrict__ kfT,
                                             const _Float16* __restrict__ vT,
                                             float* __restrict__ STf)
{
    __shared__ _Float16 sV[DD * ST_S];
    __shared__ _Float16 sK[DD * ST_S];
    const int tid = threadIdx.x;
    const int wv = tid >> 6, ln = tid & 63, lm = ln & 15, lq = ln >> 4;
    const int b = blockIdx.y;
    const int tbase = blockIdx.x * K2_KT;
    const _Float16* kb = kfT + (long)b * DD * TSEQ;
    const _Float16* vb = vT  + (long)b * DD * TSEQ;
    f4v acc[2][8];
#pragma unroll
    for (int i = 0; i < 2; ++i)
#pragma unroll
        for (int j = 0; j < 8; ++j) { acc[i][j][0]=0.f; acc[i][j][1]=0.f; acc[i][j][2]=0.f; acc[i][j][3]=0.f; }

    for (int tc = 0; tc < K2_KT; tc += K2_TC) {
        const int r = tid >> 1, c0 = (tid & 1) * 32;
        const long g = (long)r * TSEQ + tbase + tc + c0;
#pragma unroll
        for (int i = 0; i < 4; ++i) {
            *(h8v*)(sV + r * ST_S + c0 + i * 8) = *(const h8v*)(vb + g + i * 8);
            *(h8v*)(sK + r * ST_S + c0 + i * 8) = *(const h8v*)(kb + g + i * 8);
        }
        __syncthreads();
#pragma unroll
        for (int k0 = 0; k0 < 2; ++k0) {
            const h8v a0 = *(const h8v*)(sV + ((wv * 2 + 0) * 16 + lm) * ST_S + k0 * 32 + lq * 8);
            const h8v a1 = *(const h8v*)(sV + ((wv * 2 + 1) * 16 + lm) * ST_S + k0 * 32 + lq * 8);
#pragma unroll
            for (int nt = 0; nt < 8; ++nt) {
                const h8v bb = *(const h8v*)(sK + (nt * 16 + lm) * ST_S + k0 * 32 + lq * 8);
                acc[0][nt] = MFMA16(a0, bb, acc[0][nt]);
                acc[1][nt] = MFMA16(a1, bb, acc[1][nt]);
            }
        }
        __syncthreads();
    }
    float* Sb = STf + (long)b * DD * DD;
#pragma unroll
    for (int i = 0; i < 2; ++i)
#pragma unroll
        for (int nt = 0; nt < 8; ++nt)
#pragma unroll
            for (int r = 0; r < 4; ++r)
                atomicAdd(&Sb[((wv * 2 + i) * 16 + lq * 4 + r) * DD + nt * 16 + lm],
                          acc[i][nt][r]);
}

__global__ __launch_bounds__(256) void k2b_cvt(const float* __restrict__ STf,
                                               _Float16* __restrict__ STh)
{
    const int i = blockIdx.x * 256 + threadIdx.x;
    STh[i] = (_Float16)STf[i];
}

// ---------------------------------------------------------------------------
// K3: per 64-t slab: o^T[e][t] = S^T @ qf  -> RMS (shfl over e) -> o_n [t][e]
//     -> y^T[h2][t] = Wo' @ o_n -> wave maxpool over t -> atomicMax pooled.
// rms_w already folded into Wo'. LDS: sA reused for S^T then Wo'.
// ---------------------------------------------------------------------------
constexpr int K3_TC = 64;

__global__ __launch_bounds__(256) void k3_ostage(const _Float16* __restrict__ qf,
                                                 const _Float16* __restrict__ STh,
                                                 const _Float16* __restrict__ WoH,
                                                 float* __restrict__ pooled)
{
    __shared__ _Float16 sA[DD * SW_S];     // S^T [e][d], then Wo' [h2][e]
    __shared__ _Float16 sB[K3_TC * SX_S];  // qf [t][d], then o_n [t][e]
    __shared__ float sRed[4][DD];
    const int tid = threadIdx.x;
    const int wv = tid >> 6, ln = tid & 63, lm = ln & 15, lq = ln >> 4;
    const long t0 = (long)blockIdx.x * K3_TC;
    const int b = (int)(t0 >> 14);

    {   // stage S^T[b]
        const int r = tid >> 1, c0 = (tid & 1) * 64;
        const _Float16* src = STh + (long)b * DD * DD + r * DD + c0;
        _Float16* dst = sA + r * SW_S + c0;
#pragma unroll
        for (int i = 0; i < 8; ++i) *(h8v*)(dst + i * 8) = *(const h8v*)(src + i * 8);
    }
    {   // stage qf slab
        const int r = tid >> 2, c0 = (tid & 3) * 32;
        const _Float16* src = qf + (t0 + r) * DD + c0;
        _Float16* dst = sB + r * SX_S + c0;
#pragma unroll
        for (int i = 0; i < 4; ++i) *(h8v*)(dst + i * 8) = *(const h8v*)(src + i * 8);
    }
    __syncthreads();

    // o^T = S^T @ qf : wave owns t-tile wv; m = e over 8 tiles
    f4v acc[8];
#pragma unroll
    for (int i = 0; i < 8; ++i) { acc[i][0]=0.f; acc[i][1]=0.f; acc[i][2]=0.f; acc[i][3]=0.f; }
#pragma unroll
    for (int k0 = 0; k0 < 4; ++k0) {
        const h8v bf = *(const h8v*)(sB + (wv * 16 + lm) * SX_S + k0 * 32 + lq * 8);
#pragma unroll
        for (int mt = 0; mt < 8; ++mt) {
            const h8v af = *(const h8v*)(sA + (mt * 16 + lm) * SW_S + k0 * 32 + lq * 8);
            acc[mt] = MFMA16(af, bf, acc[mt]);
        }
    }
    // RMS over e (lane holds 32 of 128 e's for its t column; quads via shfl)
    float ss = 0.f;
#pragma unroll
    for (int mt = 0; mt < 8; ++mt)
#pragma unroll
        for (int r = 0; r < 4; ++r) ss += acc[mt][r] * acc[mt][r];
    ss += __shfl_xor(ss, 16, 64);
    ss += __shfl_xor(ss, 32, 64);
    const float sc = rsqrtf(ss * (1.0f / DD) + EPS);
    __syncthreads();  // all reads of sA/sB done

    // o_n -> sB [t][e]  (4 consecutive e per b64 write)
#pragma unroll
    for (int mt = 0; mt < 8; ++mt) {
        h4v h;
#pragma unroll
        for (int r = 0; r < 4; ++r) h[r] = (_Float16)(acc[mt][r] * sc);
        *(h4v*)(sB + (wv * 16 + lm) * SX_S + mt * 16 + lq * 4) = h;
    }
    {   // stage Wo' into sA
        const int r = tid >> 1, c0 = (tid & 1) * 64;
        const _Float16* src = WoH + r * DD + c0;
        _Float16* dst = sA + r * SW_S + c0;
#pragma unroll
        for (int i = 0; i < 8; ++i) *(h8v*)(dst + i * 8) = *(const h8v*)(src + i * 8);
    }
    __syncthreads();

    // y^T = Wo' @ o_n
#pragma unroll
    for (int i = 0; i < 8; ++i) { acc[i][0]=0.f; acc[i][1]=0.f; acc[i][2]=0.f; acc[i][3]=0.f; }
#pragma unroll
    for (int k0 = 0; k0 < 4; ++k0) {
        const h8v bf = *(const h8v*)(sB + (wv * 16 + lm) * SX_S + k0 * 32 + lq * 8);
#pragma unroll
        for (int mt = 0; mt < 8; ++mt) {
            const h8v af = *(const h8v*)(sA + (mt * 16 + lm) * SW_S + k0 * 32 + lq * 8);
            acc[mt] = MFMA16(af, bf, acc[mt]);
        }
    }
    // maxpool over t: reduce over the 16 n-lanes, then block-combine
#pragma unroll
    for (int mt = 0; mt < 8; ++mt)
#pragma unroll
        for (int r = 0; r < 4; ++r) {
            float m = acc[mt][r];
            m = fmaxf(m, __shfl_xor(m, 1, 64));
            m = fmaxf(m, __shfl_xor(m, 2, 64));
            m = fmaxf(m, __shfl_xor(m, 4, 64));
            m = fmaxf(m, __shfl_xor(m, 8, 64));
            if (lm == 0) sRed[wv][mt * 16 + lq * 4 + r] = m;
        }
    __syncthreads();
    if (tid < DD) {
        float m = fmaxf(fmaxf(sRed[0][tid], sRed[1][tid]),
                        fmaxf(sRed[2][tid], sRed[3][tid]));
        atomicMaxFloat(&pooled[b * DD + tid], m);
    }
}

// ---------------------------------------------------------------------------
// K4: out[b,h] = pooled[b] . Wp[h] + bp[h]
// ---------------------------------------------------------------------------
__global__ __launch_bounds__(HH) void k4_final(const float* __restrict__ pooled,
                                               const float* __restrict__ Wp,
                                               const float* __restrict__ bp,
                                               float* __restrict__ out)
{
    const int b = blockIdx.x;
    const int h = threadIdx.x;
    __shared__ float sp[DD];
    if (h < DD) sp[h] = pooled[b * DD + h];
    __syncthreads();
    float acc = bp[h];
#pragma unroll 8
    for (int d = 0; d < DD; ++d) acc = fmaf(sp[d], Wp[(long)h * DD + d], acc);
    out[b * HH + h] = acc;
}

// ---------------------------------------------------------------------------
extern "C" void kernel_launch(void* const* d_in, const int* in_sizes, int n_in,
                              void* d_out, int out_size, void* d_ws, size_t ws_size,
                              hipStream_t stream)
{
    const float* x      = (const float*)d_in[0];
    const float* Wq     = (const float*)d_in[1];
    const float* Wk     = (const float*)d_in[2];
    const float* Wv     = (const float*)d_in[3];
    const float* fmq_w1 = (const float*)d_in[4];
    const float* fmq_b1 = (const float*)d_in[5];
    const float* fmq_w2 = (const float*)d_in[6];
    const float* fmq_b2 = (const float*)d_in[7];
    const float* fmk_w1 = (const float*)d_in[8];
    const float* fmk_b1 = (const float*)d_in[9];
    const float* fmk_w2 = (const float*)d_in[10];
    const float* fmk_b2 = (const float*)d_in[11];
    const float* rms_w  = (const float*)d_in[12];
    const float* Wo     = (const float*)d_in[13];
    const float* Wp     = (const float*)d_in[14];
    const float* bp     = (const float*)d_in[15];
    float* out = (float*)d_out;

    // ws layout (fp16 unless noted): qf | kfT | vT | Wh(8 mats) | STf32 | STh | pooled
    const long nTD = (long)NB * TSEQ * DD;   // 33,554,432
    _Float16* qf  = (_Float16*)d_ws;
    _Float16* kfT = qf + nTD;
    _Float16* vT  = kfT + nTD;
    _Float16* Wh  = vT + nTD;
    float* STf    = (float*)(Wh + 8 * DD * DD);
    _Float16* STh = (_Float16*)(STf + NB * DD * DD);
    float* pooled = (float*)(STh + NB * DD * DD);

    k0_prep<<<1024, 256, 0, stream>>>(Wq, Wk, Wv, fmq_w1, fmq_w2, fmk_w1, fmk_w2,
                                      Wo, rms_w, Wh, STf, pooled);
    k1_qkvfm<<<(NB * TSEQ) / K1_BM, 256, 0, stream>>>(
        x, Wh, fmq_b1, fmq_b2, fmk_b1, fmk_b2, qf, kfT, vT);
    k2_kv<<<dim3(TSEQ / K2_KT, NB), 256, 0, stream>>>(kfT, vT, STf);
    k2b_cvt<<<(NB * DD * DD) / 256, 256, 0, stream>>>(STf, STh);
    k3_ostage<<<(NB * TSEQ) / K3_TC, 256, 0, stream>>>(qf, STh, Wh + 7 * DD * DD, pooled);
    k4_final<<<NB, HH, 0, stream>>>(pooled, Wp, bp, out);
}

// Round 4
// 475.514 us; speedup vs baseline: 3.9604x; 1.2936x over previous
//
#include <hip/hip_runtime.h>
#include <math.h>

#define NB   16
#define TSEQ 16384
#define DD   128
#define HH   256
constexpr float EPS = 1e-5f;

typedef _Float16 h8v __attribute__((ext_vector_type(8)));
typedef _Float16 h4v __attribute__((ext_vector_type(4)));
typedef float    f4v __attribute__((ext_vector_type(4)));

#define MFMA16(a, b, c) __builtin_amdgcn_mfma_f32_16x16x32_f16(a, b, c, 0, 0, 0)

// LDS strides (halves). 136*2=272B rows: 16B-aligned, 68-word stride -> 2-way
// bank alias on b128 reads (free). 72*2=144B for the [d][t] transpose view.
constexpr int SX_S = 136;
constexpr int SW_S = 136;
constexpr int ST_S = 72;

__device__ __forceinline__ void atomicMaxFloat(float* addr, float val) {
    if (val >= 0.0f) atomicMax((int*)addr, __float_as_int(val));
    else             atomicMin((unsigned int*)addr, __float_as_uint(val));
}

// ---------------------------------------------------------------------------
// K0: weights fp32->fp16 (rms_w folded into Wo), zero S^T, init pooled.
// Wh order: 0 Wq, 1 Wk, 2 Wv, 3 fq1, 4 fq2, 5 fk1, 6 fk2, 7 Wo*rms_w
// ---------------------------------------------------------------------------
__global__ __launch_bounds__(256) void k0_prep(
    const float* __restrict__ Wq, const float* __restrict__ Wk,
    const float* __restrict__ Wv, const float* __restrict__ fq1,
    const float* __restrict__ fq2, const float* __restrict__ fk1,
    const float* __restrict__ fk2, const float* __restrict__ Wo,
    const float* __restrict__ rmsw,
    _Float16* __restrict__ Wh, float* __restrict__ STf,
    float* __restrict__ pooled)
{
    const int i = blockIdx.x * 256 + threadIdx.x;
    if (i < 8 * DD * DD) {
        const int mat = i >> 14;
        const int e   = i & (DD * DD - 1);
        const float* srcs[8] = {Wq, Wk, Wv, fq1, fq2, fk1, fk2, Wo};
        float v = srcs[mat][e];
        if (mat == 7) v *= rmsw[e & (DD - 1)];
        Wh[i] = (_Float16)v;
    }
    if (i < NB * DD * DD) STf[i] = 0.0f;
    if (i < NB * DD)      pooled[i] = -INFINITY;
}

// ---------------------------------------------------------------------------
// K1 (restructured R4): 512 threads, 8 waves; wave wv owns n-tile wv (16 cols)
// over all 64 rows (4 m-tiles). Weight B-frags live in REGISTERS (4 h8v per
// matrix per wave), loaded straight from global (L2-hot) one step ahead.
// LDS = sX (x tile) + sCT (union of chain [t][d] and transpose [d][t]) =
// 35840 B -> multi-block/CU instead of the old 88 KB 1-block/CU.
// ---------------------------------------------------------------------------
__global__ __launch_bounds__(512, 4) void k1_qkvfm(
    const float* __restrict__ x, const _Float16* __restrict__ Wh,
    const float* __restrict__ bq1, const float* __restrict__ bq2,
    const float* __restrict__ bk1, const float* __restrict__ bk2,
    _Float16* __restrict__ qf, _Float16* __restrict__ kfT,
    _Float16* __restrict__ vT)
{
    __shared__ _Float16 sX[64 * SX_S];      // 17408 B
    __shared__ _Float16 sCT[DD * ST_S];     // 18432 B union: [64][136] / [128][72]

    const int tid = threadIdx.x;
    const int wv = tid >> 6;                // 0..7 -> n-tile
    const int ln = tid & 63, lm = ln & 15, lq = ln >> 4;
    const long t0 = (long)blockIdx.x * 64;
    const int b = (int)(t0 >> 14), tin = (int)(t0 & (TSEQ - 1));

    // biases for this wave's 16 columns (tiny, L2-hot)
    const float vb1q = bq1[wv * 16 + lm], vb2q = bq2[wv * 16 + lm];
    const float vb1k = bk1[wv * 16 + lm], vb2k = bk2[wv * 16 + lm];

    // stage x tile -> sX (fp32 -> fp16): 16 elems/thread
    {
        const int r = tid >> 3, c0 = (tid & 7) * 16;
        const float* src = x + (t0 + r) * DD + c0;
        _Float16* dst = sX + r * SX_S + c0;
#pragma unroll
        for (int i = 0; i < 4; ++i) {
            const float4 v = *(const float4*)(src + i * 4);
            h4v h; h[0] = (_Float16)v.x; h[1] = (_Float16)v.y;
                   h[2] = (_Float16)v.z; h[3] = (_Float16)v.w;
            *(h4v*)(dst + i * 4) = h;
        }
    }

    auto loadW = [&](int mat, h8v* w) {   // B-frags for this wave's n-tile
        const _Float16* p = Wh + mat * DD * DD + (wv * 16 + lm) * DD + lq * 8;
#pragma unroll
        for (int k0 = 0; k0 < 4; ++k0) w[k0] = *(const h8v*)(p + k0 * 32);
    };
    auto gemm = [&](const _Float16* sA, const h8v* w, f4v* acc) {
#pragma unroll
        for (int k0 = 0; k0 < 4; ++k0)
#pragma unroll
            for (int mt = 0; mt < 4; ++mt) {
                const h8v a = *(const h8v*)(sA + (mt * 16 + lm) * SX_S + k0 * 32 + lq * 8);
                acc[mt] = MFMA16(a, w[k0], acc[mt]);
            }
    };
    auto zero4 = [&](f4v* a) {
#pragma unroll
        for (int i = 0; i < 4; ++i) { a[i][0] = 0.f; a[i][1] = 0.f; a[i][2] = 0.f; a[i][3] = 0.f; }
    };
    auto cToC = [&](const f4v* a) {   // C frags -> sCT as [t][d]
#pragma unroll
        for (int mt = 0; mt < 4; ++mt)
#pragma unroll
            for (int r = 0; r < 4; ++r)
                sCT[(mt * 16 + lq * 4 + r) * SX_S + wv * 16 + lm] = (_Float16)a[mt][r];
    };
    auto cToT = [&](const f4v* a) {   // C frags -> sCT as [d][t] (h4v: 4 consec t)
#pragma unroll
        for (int mt = 0; mt < 4; ++mt) {
            h4v h;
#pragma unroll
            for (int r = 0; r < 4; ++r) h[r] = (_Float16)a[mt][r];
            *(h4v*)(sCT + (wv * 16 + lm) * ST_S + mt * 16 + lq * 4) = h;
        }
    };
    auto copyC = [&](_Float16* dst0) {    // [64][128] -> global [t][d]
        const int r = tid >> 3, c0 = (tid & 7) * 16;
        const _Float16* s = sCT + r * SX_S + c0;
        _Float16* d = dst0 + (t0 + r) * DD + c0;
        *(h8v*)(d)     = *(const h8v*)(s);
        *(h8v*)(d + 8) = *(const h8v*)(s + 8);
    };
    auto copyT = [&](_Float16* dst0) {    // [128][64] -> global [d][t]
        const int dd = tid >> 2, c0 = (tid & 3) * 16;
        const _Float16* s = sCT + dd * ST_S + c0;
        _Float16* d = dst0 + ((long)b * DD + dd) * TSEQ + tin + c0;
        *(h8v*)(d)     = *(const h8v*)(s);
        *(h8v*)(d + 8) = *(const h8v*)(s + 8);
    };

    h8v w[4], w2[4];
    f4v a1[4], a2[4];

    loadW(0, w);                               // Wq in flight during x staging
    __syncthreads();                           // B1: sX ready

    // ---------------- Q chain
    loadW(3, w2);                              // prefetch fq1
    zero4(a1); gemm(sX, w, a1);                // q
    cToC(a1);
    __syncthreads();                           // B2: sCT = q
    loadW(4, w);                               // prefetch fq2
    zero4(a1); gemm(sCT, w2, a1);              // fq1
    loadW(1, w2);                              // prefetch Wk
    zero4(a2); gemm(sCT, w, a2);               // fq2
    __syncthreads();                           // B3: all q reads done
#pragma unroll
    for (int mt = 0; mt < 4; ++mt)
#pragma unroll
        for (int r = 0; r < 4; ++r)
            a1[mt][r] = (a1[mt][r] + vb1q) * (a2[mt][r] + vb2q);
    cToC(a1);
    __syncthreads();                           // B4: sCT = qf
    copyC(qf);
    loadW(5, w);                               // prefetch fk1
    zero4(a1); gemm(sX, w2, a1);               // k (reads sX, untouched)
    __syncthreads();                           // B5: copyC reads done
    cToC(a1);
    __syncthreads();                           // B6: sCT = k
    loadW(6, w2);                              // prefetch fk2
    zero4(a1); gemm(sCT, w, a1);               // fk1
    loadW(2, w);                               // prefetch Wv
    zero4(a2); gemm(sCT, w2, a2);              // fk2
    __syncthreads();                           // B7: all k reads done
#pragma unroll
    for (int mt = 0; mt < 4; ++mt)
#pragma unroll
        for (int r = 0; r < 4; ++r)
            a1[mt][r] = (a1[mt][r] + vb1k) * (a2[mt][r] + vb2k);
    cToT(a1);
    __syncthreads();                           // B8: sCT = kf^T
    copyT(kfT);
    zero4(a1); gemm(sX, w, a1);                // v
    __syncthreads();                           // B9: copyT reads done
    cToT(a1);
    __syncthreads();                           // B10: sCT = v^T
    copyT(vT);
}

// ---------------------------------------------------------------------------
// K2: S^T[b][e][d] += sum_t vT[e][t] * kfT[d][t]   (MFMA, k = t)
// grid (T/512, NB); per block 8 staged 64-t chunks; fp32 atomicAdd partials.
// ---------------------------------------------------------------------------
constexpr int K2_KT = 512;
constexpr int K2_TC = 64;

__global__ __launch_bounds__(256) void k2_kv(const _Float16* __restrict__ kfT,
                                             const _Float16* __restrict__ vT,
                                             float* __restrict__ STf)
{
    __shared__ _Float16 sV[DD * ST_S];
    __shared__ _Float16 sK[DD * ST_S];
    const int tid = threadIdx.x;
    const int wv = tid >> 6, ln = tid & 63, lm = ln & 15, lq = ln >> 4;
    const int b = blockIdx.y;
    const int tbase = blockIdx.x * K2_KT;
    const _Float16* kb = kfT + (long)b * DD * TSEQ;
    const _Float16* vb = vT  + (long)b * DD * TSEQ;
    f4v acc[2][8];
#pragma unroll
    for (int i = 0; i < 2; ++i)
#pragma unroll
        for (int j = 0; j < 8; ++j) { acc[i][j][0]=0.f; acc[i][j][1]=0.f; acc[i][j][2]=0.f; acc[i][j][3]=0.f; }

    for (int tc = 0; tc < K2_KT; tc += K2_TC) {
        const int r = tid >> 1, c0 = (tid & 1) * 32;
        const long g = (long)r * TSEQ + tbase + tc + c0;
#pragma unroll
        for (int i = 0; i < 4; ++i) {
            *(h8v*)(sV + r * ST_S + c0 + i * 8) = *(const h8v*)(vb + g + i * 8);
            *(h8v*)(sK + r * ST_S + c0 + i * 8) = *(const h8v*)(kb + g + i * 8);
        }
        __syncthreads();
#pragma unroll
        for (int k0 = 0; k0 < 2; ++k0) {
            const h8v a0 = *(const h8v*)(sV + ((wv * 2 + 0) * 16 + lm) * ST_S + k0 * 32 + lq * 8);
            const h8v a1 = *(const h8v*)(sV + ((wv * 2 + 1) * 16 + lm) * ST_S + k0 * 32 + lq * 8);
#pragma unroll
            for (int nt = 0; nt < 8; ++nt) {
                const h8v bb = *(const h8v*)(sK + (nt * 16 + lm) * ST_S + k0 * 32 + lq * 8);
                acc[0][nt] = MFMA16(a0, bb, acc[0][nt]);
                acc[1][nt] = MFMA16(a1, bb, acc[1][nt]);
            }
        }
        __syncthreads();
    }
    float* Sb = STf + (long)b * DD * DD;
#pragma unroll
    for (int i = 0; i < 2; ++i)
#pragma unroll
        for (int nt = 0; nt < 8; ++nt)
#pragma unroll
            for (int r = 0; r < 4; ++r)
                atomicAdd(&Sb[((wv * 2 + i) * 16 + lq * 4 + r) * DD + nt * 16 + lm],
                          acc[i][nt][r]);
}

__global__ __launch_bounds__(256) void k2b_cvt(const float* __restrict__ STf,
                                               _Float16* __restrict__ STh)
{
    const int i = blockIdx.x * 256 + threadIdx.x;
    STh[i] = (_Float16)STf[i];
}

// ---------------------------------------------------------------------------
// K3: per 64-t slab: o^T[e][t] = S^T @ qf  -> RMS (shfl over e) -> o_n [t][e]
//     -> y^T[h2][t] = Wo' @ o_n -> wave maxpool over t -> atomicMax pooled.
// ---------------------------------------------------------------------------
constexpr int K3_TC = 64;

__global__ __launch_bounds__(256) void k3_ostage(const _Float16* __restrict__ qf,
                                                 const _Float16* __restrict__ STh,
                                                 const _Float16* __restrict__ WoH,
                                                 float* __restrict__ pooled)
{
    __shared__ _Float16 sA[DD * SW_S];     // S^T [e][d], then Wo' [h2][e]
    __shared__ _Float16 sB[K3_TC * SX_S];  // qf [t][d], then o_n [t][e]
    __shared__ float sRed[4][DD];
    const int tid = threadIdx.x;
    const int wv = tid >> 6, ln = tid & 63, lm = ln & 15, lq = ln >> 4;
    const long t0 = (long)blockIdx.x * K3_TC;
    const int b = (int)(t0 >> 14);

    {   // stage S^T[b]
        const int r = tid >> 1, c0 = (tid & 1) * 64;
        const _Float16* src = STh + (long)b * DD * DD + r * DD + c0;
        _Float16* dst = sA + r * SW_S + c0;
#pragma unroll
        for (int i = 0; i < 8; ++i) *(h8v*)(dst + i * 8) = *(const h8v*)(src + i * 8);
    }
    {   // stage qf slab
        const int r = tid >> 2, c0 = (tid & 3) * 32;
        const _Float16* src = qf + (t0 + r) * DD + c0;
        _Float16* dst = sB + r * SX_S + c0;
#pragma unroll
        for (int i = 0; i < 4; ++i) *(h8v*)(dst + i * 8) = *(const h8v*)(src + i * 8);
    }
    __syncthreads();

    // o^T = S^T @ qf : wave owns t-tile wv; m = e over 8 tiles
    f4v acc[8];
#pragma unroll
    for (int i = 0; i < 8; ++i) { acc[i][0]=0.f; acc[i][1]=0.f; acc[i][2]=0.f; acc[i][3]=0.f; }
#pragma unroll
    for (int k0 = 0; k0 < 4; ++k0) {
        const h8v bf = *(const h8v*)(sB + (wv * 16 + lm) * SX_S + k0 * 32 + lq * 8);
#pragma unroll
        for (int mt = 0; mt < 8; ++mt) {
            const h8v af = *(const h8v*)(sA + (mt * 16 + lm) * SW_S + k0 * 32 + lq * 8);
            acc[mt] = MFMA16(af, bf, acc[mt]);
        }
    }
    // RMS over e
    float ss = 0.f;
#pragma unroll
    for (int mt = 0; mt < 8; ++mt)
#pragma unroll
        for (int r = 0; r < 4; ++r) ss += acc[mt][r] * acc[mt][r];
    ss += __shfl_xor(ss, 16, 64);
    ss += __shfl_xor(ss, 32, 64);
    const float sc = rsqrtf(ss * (1.0f / DD) + EPS);
    __syncthreads();

    // o_n -> sB [t][e]
#pragma unroll
    for (int mt = 0; mt < 8; ++mt) {
        h4v h;
#pragma unroll
        for (int r = 0; r < 4; ++r) h[r] = (_Float16)(acc[mt][r] * sc);
        *(h4v*)(sB + (wv * 16 + lm) * SX_S + mt * 16 + lq * 4) = h;
    }
    {   // stage Wo' into sA
        const int r = tid >> 1, c0 = (tid & 1) * 64;
        const _Float16* src = WoH + r * DD + c0;
        _Float16* dst = sA + r * SW_S + c0;
#pragma unroll
        for (int i = 0; i < 8; ++i) *(h8v*)(dst + i * 8) = *(const h8v*)(src + i * 8);
    }
    __syncthreads();

    // y^T = Wo' @ o_n
#pragma unroll
    for (int i = 0; i < 8; ++i) { acc[i][0]=0.f; acc[i][1]=0.f; acc[i][2]=0.f; acc[i][3]=0.f; }
#pragma unroll
    for (int k0 = 0; k0 < 4; ++k0) {
        const h8v bf = *(const h8v*)(sB + (wv * 16 + lm) * SX_S + k0 * 32 + lq * 8);
#pragma unroll
        for (int mt = 0; mt < 8; ++mt) {
            const h8v af = *(const h8v*)(sA + (mt * 16 + lm) * SW_S + k0 * 32 + lq * 8);
            acc[mt] = MFMA16(af, bf, acc[mt]);
        }
    }
    // maxpool over t
#pragma unroll
    for (int mt = 0; mt < 8; ++mt)
#pragma unroll
        for (int r = 0; r < 4; ++r) {
            float m = acc[mt][r];
            m = fmaxf(m, __shfl_xor(m, 1, 64));
            m = fmaxf(m, __shfl_xor(m, 2, 64));
            m = fmaxf(m, __shfl_xor(m, 4, 64));
            m = fmaxf(m, __shfl_xor(m, 8, 64));
            if (lm == 0) sRed[wv][mt * 16 + lq * 4 + r] = m;
        }
    __syncthreads();
    if (tid < DD) {
        float m = fmaxf(fmaxf(sRed[0][tid], sRed[1][tid]),
                        fmaxf(sRed[2][tid], sRed[3][tid]));
        atomicMaxFloat(&pooled[b * DD + tid], m);
    }
}

// ---------------------------------------------------------------------------
// K4: out[b,h] = pooled[b] . Wp[h] + bp[h]
// ---------------------------------------------------------------------------
__global__ __launch_bounds__(HH) void k4_final(const float* __restrict__ pooled,
                                               const float* __restrict__ Wp,
                                               const float* __restrict__ bp,
                                               float* __restrict__ out)
{
    const int b = blockIdx.x;
    const int h = threadIdx.x;
    __shared__ float sp[DD];
    if (h < DD) sp[h] = pooled[b * DD + h];
    __syncthreads();
    float acc = bp[h];
#pragma unroll 8
    for (int d = 0; d < DD; ++d) acc = fmaf(sp[d], Wp[(long)h * DD + d], acc);
    out[b * HH + h] = acc;
}

// ---------------------------------------------------------------------------
extern "C" void kernel_launch(void* const* d_in, const int* in_sizes, int n_in,
                              void* d_out, int out_size, void* d_ws, size_t ws_size,
                              hipStream_t stream)
{
    const float* x      = (const float*)d_in[0];
    const float* Wq     = (const float*)d_in[1];
    const float* Wk     = (const float*)d_in[2];
    const float* Wv     = (const float*)d_in[3];
    const float* fmq_w1 = (const float*)d_in[4];
    const float* fmq_b1 = (const float*)d_in[5];
    const float* fmq_w2 = (const float*)d_in[6];
    const float* fmq_b2 = (const float*)d_in[7];
    const float* fmk_w1 = (const float*)d_in[8];
    const float* fmk_b1 = (const float*)d_in[9];
    const float* fmk_w2 = (const float*)d_in[10];
    const float* fmk_b2 = (const float*)d_in[11];
    const float* rms_w  = (const float*)d_in[12];
    const float* Wo     = (const float*)d_in[13];
    const float* Wp     = (const float*)d_in[14];
    const float* bp     = (const float*)d_in[15];
    float* out = (float*)d_out;

    // ws layout (fp16 unless noted): qf | kfT | vT | Wh(8 mats) | STf32 | STh | pooled
    const long nTD = (long)NB * TSEQ * DD;   // 33,554,432
    _Float16* qf  = (_Float16*)d_ws;
    _Float16* kfT = qf + nTD;
    _Float16* vT  = kfT + nTD;
    _Float16* Wh  = vT + nTD;
    float* STf    = (float*)(Wh + 8 * DD * DD);
    _Float16* STh = (_Float16*)(STf + NB * DD * DD);
    float* pooled = (float*)(STh + NB * DD * DD);

    k0_prep<<<1024, 256, 0, stream>>>(Wq, Wk, Wv, fmq_w1, fmq_w2, fmk_w1, fmk_w2,
                                      Wo, rms_w, Wh, STf, pooled);
    k1_qkvfm<<<(NB * TSEQ) / 64, 512, 0, stream>>>(
        x, Wh, fmq_b1, fmq_b2, fmk_b1, fmk_b2, qf, kfT, vT);
    k2_kv<<<dim3(TSEQ / K2_KT, NB), 256, 0, stream>>>(kfT, vT, STf);
    k2b_cvt<<<(NB * DD * DD) / 256, 256, 0, stream>>>(STf, STh);
    k3_ostage<<<(NB * TSEQ) / K3_TC, 256, 0, stream>>>(qf, STh, Wh + 7 * DD * DD, pooled);
    k4_final<<<NB, HH, 0, stream>>>(pooled, Wp, bp, out);
}

// Round 7
// 470.303 us; speedup vs baseline: 4.0042x; 1.0111x over previous
//
#include <hip/hip_runtime.h>
#include <math.h>

#define NB   16
#define TSEQ 16384
#define DD   128
#define HH   256
constexpr float EPS = 1e-5f;

typedef _Float16 h8v __attribute__((ext_vector_type(8)));
typedef _Float16 h4v __attribute__((ext_vector_type(4)));
typedef float    f4v __attribute__((ext_vector_type(4)));

#define MFMA16(a, b, c) __builtin_amdgcn_mfma_f32_16x16x32_f16(a, b, c, 0, 0, 0)

// LDS strides (halves). 136*2=272B rows: 16B-aligned, 68-word stride -> 2-way
// bank alias on b128 reads (free). 72*2=144B for the [d][t] transpose view.
constexpr int SX_S = 136;
constexpr int SW_S = 136;
constexpr int ST_S = 72;

__device__ __forceinline__ void atomicMaxFloat(float* addr, float val) {
    if (val >= 0.0f) atomicMax((int*)addr, __float_as_int(val));
    else             atomicMin((unsigned int*)addr, __float_as_uint(val));
}

// ---------------------------------------------------------------------------
// K0: weights fp32->fp16 (rms_w folded into Wo), init pooled.
// Wh order: 0 Wq, 1 Wk, 2 Wv, 3 fq1, 4 fq2, 5 fk1, 6 fk2, 7 Wo*rms_w
// Grid: 512 x 256 covers 8*DD*DD = 131072.
// ---------------------------------------------------------------------------
__global__ __launch_bounds__(256) void k0_prep(
    const float* __restrict__ Wq, const float* __restrict__ Wk,
    const float* __restrict__ Wv, const float* __restrict__ fq1,
    const float* __restrict__ fq2, const float* __restrict__ fk1,
    const float* __restrict__ fk2, const float* __restrict__ Wo,
    const float* __restrict__ rmsw,
    _Float16* __restrict__ Wh, float* __restrict__ pooled)
{
    const int i = blockIdx.x * 256 + threadIdx.x;
    if (i < 8 * DD * DD) {
        const int mat = i >> 14;
        const int e   = i & (DD * DD - 1);
        const float* srcs[8] = {Wq, Wk, Wv, fq1, fq2, fk1, fk2, Wo};
        float v = srcs[mat][e];
        if (mat == 7) v *= rmsw[e & (DD - 1)];
        Wh[i] = (_Float16)v;
    }
    if (i < NB * DD)      pooled[i] = -INFINITY;
}

// ---------------------------------------------------------------------------
// K1 (R4 structure, unchanged): 512 threads, 8 waves; wave wv owns n-tile wv.
// Weight B-frags in registers, prefetched one gemm ahead. LDS 35840 B.
// ---------------------------------------------------------------------------
__global__ __launch_bounds__(512, 4) void k1_qkvfm(
    const float* __restrict__ x, const _Float16* __restrict__ Wh,
    const float* __restrict__ bq1, const float* __restrict__ bq2,
    const float* __restrict__ bk1, const float* __restrict__ bk2,
    _Float16* __restrict__ qf, _Float16* __restrict__ kfT,
    _Float16* __restrict__ vT)
{
    __shared__ _Float16 sX[64 * SX_S];      // 17408 B
    __shared__ _Float16 sCT[DD * ST_S];     // 18432 B union: [64][136] / [128][72]

    const int tid = threadIdx.x;
    const int wv = tid >> 6;                // 0..7 -> n-tile
    const int ln = tid & 63, lm = ln & 15, lq = ln >> 4;
    const long t0 = (long)blockIdx.x * 64;
    const int b = (int)(t0 >> 14), tin = (int)(t0 & (TSEQ - 1));

    const float vb1q = bq1[wv * 16 + lm], vb2q = bq2[wv * 16 + lm];
    const float vb1k = bk1[wv * 16 + lm], vb2k = bk2[wv * 16 + lm];

    {
        const int r = tid >> 3, c0 = (tid & 7) * 16;
        const float* src = x + (t0 + r) * DD + c0;
        _Float16* dst = sX + r * SX_S + c0;
#pragma unroll
        for (int i = 0; i < 4; ++i) {
            const float4 v = *(const float4*)(src + i * 4);
            h4v h; h[0] = (_Float16)v.x; h[1] = (_Float16)v.y;
                   h[2] = (_Float16)v.z; h[3] = (_Float16)v.w;
            *(h4v*)(dst + i * 4) = h;
        }
    }

    auto loadW = [&](int mat, h8v* w) {
        const _Float16* p = Wh + mat * DD * DD + (wv * 16 + lm) * DD + lq * 8;
#pragma unroll
        for (int k0 = 0; k0 < 4; ++k0) w[k0] = *(const h8v*)(p + k0 * 32);
    };
    auto gemm = [&](const _Float16* sA, const h8v* w, f4v* acc) {
#pragma unroll
        for (int k0 = 0; k0 < 4; ++k0)
#pragma unroll
            for (int mt = 0; mt < 4; ++mt) {
                const h8v a = *(const h8v*)(sA + (mt * 16 + lm) * SX_S + k0 * 32 + lq * 8);
                acc[mt] = MFMA16(a, w[k0], acc[mt]);
            }
    };
    auto zero4 = [&](f4v* a) {
#pragma unroll
        for (int i = 0; i < 4; ++i) { a[i][0] = 0.f; a[i][1] = 0.f; a[i][2] = 0.f; a[i][3] = 0.f; }
    };
    auto cToC = [&](const f4v* a) {
#pragma unroll
        for (int mt = 0; mt < 4; ++mt)
#pragma unroll
            for (int r = 0; r < 4; ++r)
                sCT[(mt * 16 + lq * 4 + r) * SX_S + wv * 16 + lm] = (_Float16)a[mt][r];
    };
    auto cToT = [&](const f4v* a) {
#pragma unroll
        for (int mt = 0; mt < 4; ++mt) {
            h4v h;
#pragma unroll
            for (int r = 0; r < 4; ++r) h[r] = (_Float16)a[mt][r];
            *(h4v*)(sCT + (wv * 16 + lm) * ST_S + mt * 16 + lq * 4) = h;
        }
    };
    auto copyC = [&](_Float16* dst0) {
        const int r = tid >> 3, c0 = (tid & 7) * 16;
        const _Float16* s = sCT + r * SX_S + c0;
        _Float16* d = dst0 + (t0 + r) * DD + c0;
        *(h8v*)(d)     = *(const h8v*)(s);
        *(h8v*)(d + 8) = *(const h8v*)(s + 8);
    };
    auto copyT = [&](_Float16* dst0) {
        const int dd = tid >> 2, c0 = (tid & 3) * 16;
        const _Float16* s = sCT + dd * ST_S + c0;
        _Float16* d = dst0 + ((long)b * DD + dd) * TSEQ + tin + c0;
        *(h8v*)(d)     = *(const h8v*)(s);
        *(h8v*)(d + 8) = *(const h8v*)(s + 8);
    };

    h8v w[4], w2[4];
    f4v a1[4], a2[4];

    loadW(0, w);
    __syncthreads();                           // B1: sX ready

    // ---------------- Q chain
    loadW(3, w2);
    zero4(a1); gemm(sX, w, a1);                // q
    cToC(a1);
    __syncthreads();                           // B2: sCT = q
    loadW(4, w);
    zero4(a1); gemm(sCT, w2, a1);              // fq1
    loadW(1, w2);
    zero4(a2); gemm(sCT, w, a2);               // fq2
    __syncthreads();                           // B3
#pragma unroll
    for (int mt = 0; mt < 4; ++mt)
#pragma unroll
        for (int r = 0; r < 4; ++r)
            a1[mt][r] = (a1[mt][r] + vb1q) * (a2[mt][r] + vb2q);
    cToC(a1);
    __syncthreads();                           // B4: sCT = qf
    copyC(qf);
    loadW(5, w);
    zero4(a1); gemm(sX, w2, a1);               // k
    __syncthreads();                           // B5
    cToC(a1);
    __syncthreads();                           // B6: sCT = k
    loadW(6, w2);
    zero4(a1); gemm(sCT, w, a1);               // fk1
    loadW(2, w);
    zero4(a2); gemm(sCT, w2, a2);              // fk2
    __syncthreads();                           // B7
#pragma unroll
    for (int mt = 0; mt < 4; ++mt)
#pragma unroll
        for (int r = 0; r < 4; ++r)
            a1[mt][r] = (a1[mt][r] + vb1k) * (a2[mt][r] + vb2k);
    cToT(a1);
    __syncthreads();                           // B8: sCT = kf^T
    copyT(kfT);
    zero4(a1); gemm(sX, w, a1);                // v
    __syncthreads();                           // B9
    cToT(a1);
    __syncthreads();                           // B10: sCT = v^T
    copyT(vT);
}

// ---------------------------------------------------------------------------
// K2 (split-K, NO atomics): grid (64, NB) = 1024 blocks (4/CU resident).
// Each block reduces 256 t's and STORES its [128][128] fp32 partial to
// STf[(b*64 + cx) * 16384] contiguously.
// ---------------------------------------------------------------------------
constexpr int K2_KT = 256;                    // t per block
constexpr int K2_TC = 64;                     // t per staged chunk
constexpr int K2_SPLIT = TSEQ / K2_KT;        // 64 partials per batch

__global__ __launch_bounds__(256, 4) void k2_kv(const _Float16* __restrict__ kfT,
                                                const _Float16* __restrict__ vT,
                                                float* __restrict__ STf)
{
    __shared__ _Float16 sV[DD * ST_S];
    __shared__ _Float16 sK[DD * ST_S];
    const int tid = threadIdx.x;
    const int wv = tid >> 6, ln = tid & 63, lm = ln & 15, lq = ln >> 4;
    const int b = blockIdx.y;
    const int tbase = blockIdx.x * K2_KT;
    const _Float16* kb = kfT + (long)b * DD * TSEQ;
    const _Float16* vb = vT  + (long)b * DD * TSEQ;
    f4v acc[2][8];
#pragma unroll
    for (int i = 0; i < 2; ++i)
#pragma unroll
        for (int j = 0; j < 8; ++j) { acc[i][j][0]=0.f; acc[i][j][1]=0.f; acc[i][j][2]=0.f; acc[i][j][3]=0.f; }

    for (int tc = 0; tc < K2_KT; tc += K2_TC) {
        const int r = tid >> 1, c0 = (tid & 1) * 32;
        const long g = (long)r * TSEQ + tbase + tc + c0;
#pragma unroll
        for (int i = 0; i < 4; ++i) {
            *(h8v*)(sV + r * ST_S + c0 + i * 8) = *(const h8v*)(vb + g + i * 8);
            *(h8v*)(sK + r * ST_S + c0 + i * 8) = *(const h8v*)(kb + g + i * 8);
        }
        __syncthreads();
#pragma unroll
        for (int k0 = 0; k0 < 2; ++k0) {
            const h8v a0 = *(const h8v*)(sV + ((wv * 2 + 0) * 16 + lm) * ST_S + k0 * 32 + lq * 8);
            const h8v a1 = *(const h8v*)(sV + ((wv * 2 + 1) * 16 + lm) * ST_S + k0 * 32 + lq * 8);
#pragma unroll
            for (int nt = 0; nt < 8; ++nt) {
                const h8v bb = *(const h8v*)(sK + (nt * 16 + lm) * ST_S + k0 * 32 + lq * 8);
                acc[0][nt] = MFMA16(a0, bb, acc[0][nt]);
                acc[1][nt] = MFMA16(a1, bb, acc[1][nt]);
            }
        }
        __syncthreads();
    }
    // store this block's partial (contiguous 64 KB region, plain stores)
    float* Pb = STf + (long)(b * K2_SPLIT + blockIdx.x) * (DD * DD);
#pragma unroll
    for (int i = 0; i < 2; ++i)
#pragma unroll
        for (int nt = 0; nt < 8; ++nt)
#pragma unroll
            for (int r = 0; r < 4; ++r)
                Pb[((wv * 2 + i) * 16 + lq * 4 + r) * DD + nt * 16 + lm] = acc[i][nt][r];
}

// ---------------------------------------------------------------------------
// K2r: sum the 64 split-K partials per batch -> fp16 S^T. Coalesced.
// ---------------------------------------------------------------------------
__global__ __launch_bounds__(256) void k2r_reduce(const float* __restrict__ STf,
                                                  _Float16* __restrict__ STh)
{
    const int idx = blockIdx.x * 256 + threadIdx.x;     // 0 .. NB*16384-1
    const int b = idx >> 14, e = idx & (DD * DD - 1);
    const float* p = STf + (long)b * K2_SPLIT * (DD * DD) + e;
    float s0 = 0.f, s1 = 0.f, s2 = 0.f, s3 = 0.f;
#pragma unroll
    for (int j = 0; j < K2_SPLIT; j += 4) {
        s0 += p[(long)(j + 0) * (DD * DD)];
        s1 += p[(long)(j + 1) * (DD * DD)];
        s2 += p[(long)(j + 2) * (DD * DD)];
        s3 += p[(long)(j + 3) * (DD * DD)];
    }
    STh[idx] = (_Float16)((s0 + s1) + (s2 + s3));
}

// ---------------------------------------------------------------------------
// K3 (128-t slabs, 512 threads / 8 waves):
//   o^T[e][t] = S^T @ qf -> RMS (shfl over e) -> o_n [t][e]
//   -> y^T[h'][t] = Wo' @ o_n -> maxpool over t -> atomicMax pooled.
// R6 BUG FIXED: staging wrote only 2 h8v of the needed 4 per thread
// (cols [c0+16,c0+32) of every row were poison). Now 4 h8v = 32 halves.
// ---------------------------------------------------------------------------
constexpr int K3_TC = 128;

__global__ __launch_bounds__(512, 4) void k3_ostage(const _Float16* __restrict__ qf,
                                                    const _Float16* __restrict__ STh,
                                                    const _Float16* __restrict__ WoH,
                                                    float* __restrict__ pooled)
{
    __shared__ _Float16 sA[DD * SW_S];      // S^T [e][d], then Wo' [h'][e]  34816 B
    __shared__ _Float16 sB[K3_TC * SX_S];   // qf [t][d], then o_n [t][e]    34816 B
    __shared__ float sRed[8][DD];           // 4096 B
    const int tid = threadIdx.x;
    const int wv = tid >> 6, ln = tid & 63, lm = ln & 15, lq = ln >> 4;
    const long t0 = (long)blockIdx.x * K3_TC;
    const int b = (int)(t0 >> 14);

    {   // stage S^T[b]: 128 rows x 128 cols; 512 thr x 32 halves (4 h8v)
        const int r = tid >> 2, c0 = (tid & 3) * 32;
        const _Float16* src = STh + (long)b * DD * DD + r * DD + c0;
        _Float16* dst = sA + r * SW_S + c0;
        *(h8v*)(dst)      = *(const h8v*)(src);
        *(h8v*)(dst + 8)  = *(const h8v*)(src + 8);
        *(h8v*)(dst + 16) = *(const h8v*)(src + 16);
        *(h8v*)(dst + 24) = *(const h8v*)(src + 24);
    }
    {   // stage qf slab: 128 t x 128 d; 4 h8v per thread
        const int r = tid >> 2, c0 = (tid & 3) * 32;
        const _Float16* src = qf + (t0 + r) * DD + c0;
        _Float16* dst = sB + r * SX_S + c0;
        *(h8v*)(dst)      = *(const h8v*)(src);
        *(h8v*)(dst + 8)  = *(const h8v*)(src + 8);
        *(h8v*)(dst + 16) = *(const h8v*)(src + 16);
        *(h8v*)(dst + 24) = *(const h8v*)(src + 24);
    }
    __syncthreads();                        // B1

    // o^T = S^T @ qf : wave wv owns t-tile wv (16 t); m = e over 8 tiles
    f4v acc[8];
#pragma unroll
    for (int i = 0; i < 8; ++i) { acc[i][0]=0.f; acc[i][1]=0.f; acc[i][2]=0.f; acc[i][3]=0.f; }
#pragma unroll
    for (int k0 = 0; k0 < 4; ++k0) {
        const h8v bf = *(const h8v*)(sB + (wv * 16 + lm) * SX_S + k0 * 32 + lq * 8);
#pragma unroll
        for (int mt = 0; mt < 8; ++mt) {
            const h8v af = *(const h8v*)(sA + (mt * 16 + lm) * SW_S + k0 * 32 + lq * 8);
            acc[mt] = MFMA16(af, bf, acc[mt]);
        }
    }
    // RMS over e (lane's t = wv*16+lm; e quads spread over lq -> shfl 16,32)
    float ss = 0.f;
#pragma unroll
    for (int mt = 0; mt < 8; ++mt)
#pragma unroll
        for (int r = 0; r < 4; ++r) ss += acc[mt][r] * acc[mt][r];
    ss += __shfl_xor(ss, 16, 64);
    ss += __shfl_xor(ss, 32, 64);
    const float sc = rsqrtf(ss * (1.0f / DD) + EPS);

    // o_n -> sB rows of OWN wave's t-tile (exclusive; safe pre-barrier)
#pragma unroll
    for (int mt = 0; mt < 8; ++mt) {
        h4v h;
#pragma unroll
        for (int r = 0; r < 4; ++r) h[r] = (_Float16)(acc[mt][r] * sc);
        *(h4v*)(sB + (wv * 16 + lm) * SX_S + mt * 16 + lq * 4) = h;
    }
    __syncthreads();                        // B2: all sA reads done
    {   // stage Wo' into sA; 4 h8v per thread
        const int r = tid >> 2, c0 = (tid & 3) * 32;
        const _Float16* src = WoH + r * DD + c0;
        _Float16* dst = sA + r * SW_S + c0;
        *(h8v*)(dst)      = *(const h8v*)(src);
        *(h8v*)(dst + 8)  = *(const h8v*)(src + 8);
        *(h8v*)(dst + 16) = *(const h8v*)(src + 16);
        *(h8v*)(dst + 24) = *(const h8v*)(src + 24);
    }
    __syncthreads();                        // B3

    // y^T = Wo' @ o_n
#pragma unroll
    for (int i = 0; i < 8; ++i) { acc[i][0]=0.f; acc[i][1]=0.f; acc[i][2]=0.f; acc[i][3]=0.f; }
#pragma unroll
    for (int k0 = 0; k0 < 4; ++k0) {
        const h8v bf = *(const h8v*)(sB + (wv * 16 + lm) * SX_S + k0 * 32 + lq * 8);
#pragma unroll
        for (int mt = 0; mt < 8; ++mt) {
            const h8v af = *(const h8v*)(sA + (mt * 16 + lm) * SW_S + k0 * 32 + lq * 8);
            acc[mt] = MFMA16(af, bf, acc[mt]);
        }
    }
    // maxpool over t: within-wave over the 16 n-lanes, then across 8 waves
#pragma unroll
    for (int mt = 0; mt < 8; ++mt)
#pragma unroll
        for (int r = 0; r < 4; ++r) {
            float m = acc[mt][r];
            m = fmaxf(m, __shfl_xor(m, 1, 64));
            m = fmaxf(m, __shfl_xor(m, 2, 64));
            m = fmaxf(m, __shfl_xor(m, 4, 64));
            m = fmaxf(m, __shfl_xor(m, 8, 64));
            if (lm == 0) sRed[wv][mt * 16 + lq * 4 + r] = m;
        }
    __syncthreads();                        // B4
    if (tid < DD) {
        float m = sRed[0][tid];
#pragma unroll
        for (int r = 1; r < 8; ++r) m = fmaxf(m, sRed[r][tid]);
        atomicMaxFloat(&pooled[b * DD + tid], m);
    }
}

// ---------------------------------------------------------------------------
// K4: out[b,h] = pooled[b] . Wp[h] + bp[h]
// ---------------------------------------------------------------------------
__global__ __launch_bounds__(HH) void k4_final(const float* __restrict__ pooled,
                                               const float* __restrict__ Wp,
                                               const float* __restrict__ bp,
                                               float* __restrict__ out)
{
    const int b = blockIdx.x;
    const int h = threadIdx.x;
    __shared__ float sp[DD];
    if (h < DD) sp[h] = pooled[b * DD + h];
    __syncthreads();
    float acc = bp[h];
#pragma unroll 8
    for (int d = 0; d < DD; ++d) acc = fmaf(sp[d], Wp[(long)h * DD + d], acc);
    out[b * HH + h] = acc;
}

// ---------------------------------------------------------------------------
extern "C" void kernel_launch(void* const* d_in, const int* in_sizes, int n_in,
                              void* d_out, int out_size, void* d_ws, size_t ws_size,
                              hipStream_t stream)
{
    const float* x      = (const float*)d_in[0];
    const float* Wq     = (const float*)d_in[1];
    const float* Wk     = (const float*)d_in[2];
    const float* Wv     = (const float*)d_in[3];
    const float* fmq_w1 = (const float*)d_in[4];
    const float* fmq_b1 = (const float*)d_in[5];
    const float* fmq_w2 = (const float*)d_in[6];
    const float* fmq_b2 = (const float*)d_in[7];
    const float* fmk_w1 = (const float*)d_in[8];
    const float* fmk_b1 = (const float*)d_in[9];
    const float* fmk_w2 = (const float*)d_in[10];
    const float* fmk_b2 = (const float*)d_in[11];
    const float* rms_w  = (const float*)d_in[12];
    const float* Wo     = (const float*)d_in[13];
    const float* Wp     = (const float*)d_in[14];
    const float* bp     = (const float*)d_in[15];
    float* out = (float*)d_out;

    // ws layout: qf | kfT | vT (fp16) | Wh (fp16) | STf (fp32 split-K partials)
    //            | STh (fp16) | pooled (fp32)   -- ~269 MB total
    const long nTD = (long)NB * TSEQ * DD;   // 33,554,432
    _Float16* qf  = (_Float16*)d_ws;
    _Float16* kfT = qf + nTD;
    _Float16* vT  = kfT + nTD;
    _Float16* Wh  = vT + nTD;
    float* STf    = (float*)(Wh + 8 * DD * DD);              // NB*64*16384 fp32
    _Float16* STh = (_Float16*)(STf + (long)NB * K2_SPLIT * DD * DD);
    float* pooled = (float*)(STh + NB * DD * DD);

    k0_prep<<<512, 256, 0, stream>>>(Wq, Wk, Wv, fmq_w1, fmq_w2, fmk_w1, fmk_w2,
                                     Wo, rms_w, Wh, pooled);
    k1_qkvfm<<<(NB * TSEQ) / 64, 512, 0, stream>>>(
        x, Wh, fmq_b1, fmq_b2, fmk_b1, fmk_b2, qf, kfT, vT);
    k2_kv<<<dim3(K2_SPLIT, NB), 256, 0, stream>>>(kfT, vT, STf);
    k2r_reduce<<<(NB * DD * DD) / 256, 256, 0, stream>>>(STf, STh);
    k3_ostage<<<(NB * TSEQ) / K3_TC, 512, 0, stream>>>(qf, STh, Wh + 7 * DD * DD, pooled);
    k4_final<<<NB, HH, 0, stream>>>(pooled, Wp, bp, out);
}